// Round 1
// baseline (519.528 us; speedup 1.0000x reference)
//
#include <hip/hip_runtime.h>
#include <hip/hip_bf16.h>
#include <stdint.h>

// Problem constants
#define BATCH 8
#define SEQ   4096
#define DM    512
#define HD    120
#define KP    128   // padded k-dim for MFMA (120 -> 128, zero pad)

typedef __bf16   v8bf  __attribute__((ext_vector_type(8)));
typedef float    v4f   __attribute__((ext_vector_type(4)));
typedef uint32_t u32x4 __attribute__((ext_vector_type(4)));
typedef float    f32x4 __attribute__((ext_vector_type(4)));

static __device__ __forceinline__ ushort f2bf(float x) {
  // round-to-nearest-even f32 -> bf16 (values are bounded, no NaN/Inf concern)
  uint32_t u = __builtin_bit_cast(uint32_t, x);
  return (ushort)((u + 0x7fffu + ((u >> 16) & 1u)) >> 16);
}

// -------------------------------------------------------------------------
// Kernel 1: ctx_n = normalize((query @ w_q^T + b_q) * wt)  -> bf16 [B*S][128]
// f32 on VALU (precision), LDS-tiled. 512 blocks x 256 threads, 64 rows/block.
// -------------------------------------------------------------------------
__global__ __launch_bounds__(256) void ctx_kernel(
    const float* __restrict__ q, const float* __restrict__ wq,
    const float* __restrict__ bq, const float* __restrict__ wt,
    ushort* __restrict__ ctx)
{
  __shared__ float qs[64][33];    // [row][k-chunk], +1 pad
  __shared__ float ws[32][132];   // [k][col], pad 132 keeps banks spread, 16B aligned rows

  const int t  = threadIdx.x;
  const int ty = t >> 4, tx = t & 15;     // thread -> 4 rows (ty*4..), 8 cols (tx*8..)
  const size_t row0 = (size_t)blockIdx.x * 64;

  float acc[4][8];
  #pragma unroll
  for (int j = 0; j < 4; ++j)
    #pragma unroll
    for (int i = 0; i < 8; ++i) acc[j][i] = 0.f;

  for (int k0 = 0; k0 < DM; k0 += 32) {
    __syncthreads();
    #pragma unroll
    for (int i = 0; i < 8; ++i) {          // q chunk: 64x32
      int flat = t + i * 256;
      int r = flat >> 5, kk = flat & 31;
      qs[r][kk] = q[(row0 + r) * DM + k0 + kk];
    }
    #pragma unroll
    for (int i = 0; i < 16; ++i) {         // w chunk (transposed): 32x128, zero pad c>=120
      int flat = t + i * 256;
      int kk = flat & 31, c = flat >> 5;
      ws[kk][c] = (c < HD) ? wq[c * DM + k0 + kk] : 0.f;
    }
    __syncthreads();
    #pragma unroll
    for (int kk = 0; kk < 32; ++kk) {
      float a[4];
      #pragma unroll
      for (int j = 0; j < 4; ++j) a[j] = qs[ty * 4 + j][kk];
      f32x4 b0 = *(const f32x4*)&ws[kk][tx * 8];
      f32x4 b1 = *(const f32x4*)&ws[kk][tx * 8 + 4];
      float bb[8] = {b0[0], b0[1], b0[2], b0[3], b1[0], b1[1], b1[2], b1[3]};
      #pragma unroll
      for (int j = 0; j < 4; ++j)
        #pragma unroll
        for (int i = 0; i < 8; ++i)
          acc[j][i] = fmaf(a[j], bb[i], acc[j][i]);
    }
  }

  float wtv[8], bqv[8];
  #pragma unroll
  for (int i = 0; i < 8; ++i) {
    int c = tx * 8 + i;
    wtv[i] = (c < HD) ? wt[c] : 0.f;
    bqv[i] = (c < HD) ? bq[c] : 0.f;
  }
  #pragma unroll
  for (int j = 0; j < 4; ++j) {
    float v[8]; float ss = 0.f;
    #pragma unroll
    for (int i = 0; i < 8; ++i) {
      v[i] = (acc[j][i] + bqv[i]) * wtv[i];
      ss = fmaf(v[i], v[i], ss);
    }
    #pragma unroll
    for (int xm = 1; xm < 16; xm <<= 1) ss += __shfl_xor(ss, xm, 64);
    float rinv = 1.f / fmaxf(sqrtf(ss), 1e-12f);
    uint32_t pk[4];
    #pragma unroll
    for (int i = 0; i < 4; ++i) {
      uint32_t lo = f2bf(v[2 * i] * rinv);
      uint32_t hi = f2bf(v[2 * i + 1] * rinv);
      pk[i] = lo | (hi << 16);
    }
    u32x4 o = {pk[0], pk[1], pk[2], pk[3]};
    *(u32x4*)&ctx[(row0 + ty * 4 + j) * KP + tx * 8] = o;
  }
}

// -------------------------------------------------------------------------
// Kernel 2: scores + mask + softmax, two-pass recompute (online m,l in pass A).
// 512 blocks (batch = blockIdx%8 -> XCD-local ctx), 512 threads (8 waves 2x4).
// Block tile: 64 q-rows x 4096 cols, col tile 128, K=128 (4 MFMA k-steps).
// -------------------------------------------------------------------------
static __device__ __forceinline__ v8bf ldfrag(const ushort* s, int row, int kb) {
  int byte = row * 256 + (kb ^ ((row & 7) << 4));   // XOR swizzle (G4)
  u32x4 u = *(const u32x4*)((const char*)s + byte);
  return __builtin_bit_cast(v8bf, u);
}

__global__ __launch_bounds__(512) void attn_kernel(
    const ushort* __restrict__ ctx, const int* __restrict__ mask,
    uint32_t* __restrict__ wsbits, float* __restrict__ out)
{
  __shared__ ushort A_s[64 * KP];
  __shared__ ushort B_s[128 * KP];
  __shared__ float mW[4][64], lW[4][64];
  __shared__ float mfin[64], lfin[64];

  const int t    = threadIdx.x;
  const int b    = blockIdx.x & 7;
  const int tile = blockIdx.x >> 3;
  const int r0   = tile * 64;
  const int w    = t >> 6, lane = t & 63;
  const int wr   = w >> 2, wc = w & 3;     // wave tile: 32 rows x 32 cols
  const int g    = lane >> 4, ln = lane & 15;
  const ushort* ctxb = ctx + (size_t)b * SEQ * KP;
  uint32_t* wsb = wsbits + (size_t)blockIdx.x * (512 * 16);

  // stage A rows (64x128 bf16), swizzled
  #pragma unroll
  for (int jj = 0; jj < 2; ++jj) {
    int c = t * 2 + jj;
    int row = c >> 4, slot = c & 15;
    u32x4 v = *(const u32x4*)(ctxb + (size_t)(r0 + row) * KP + slot * 8);
    *(u32x4*)((char*)A_s + row * 256 + ((slot * 16) ^ ((row & 7) << 4))) = v;
  }

  float m_run[2][4], l_run[2][4];
  #pragma unroll
  for (int rs = 0; rs < 2; ++rs)
    #pragma unroll
    for (int i = 0; i < 4; ++i) { m_run[rs][i] = -3e38f; l_run[rs][i] = 0.f; }

  const size_t mbase = ((size_t)b << 24) + ((size_t)r0 << 12);
  uint32_t curbits = 0;

  // ---------------- PASS A: online max/sum + mask-bit packing ----------------
  for (int j = 0; j < 32; ++j) {
    __syncthreads();
    #pragma unroll
    for (int jj = 0; jj < 4; ++jj) {         // stage B col tile 128x128 bf16
      int c = t * 4 + jj;
      int row = c >> 4, slot = c & 15;
      u32x4 v = *(const u32x4*)(ctxb + (size_t)(j * 128 + row) * KP + slot * 8);
      *(u32x4*)((char*)B_s + row * 256 + ((slot * 16) ^ ((row & 7) << 4))) = v;
    }
    __syncthreads();

    v4f acc[2][2];
    #pragma unroll
    for (int rs = 0; rs < 2; ++rs)
      #pragma unroll
      for (int cs = 0; cs < 2; ++cs) acc[rs][cs] = (v4f){0.f, 0.f, 0.f, 0.f};
    #pragma unroll
    for (int kk = 0; kk < 4; ++kk) {
      int kb = kk * 64 + g * 16;
      v8bf a0 = ldfrag(A_s, wr * 32 + ln,      kb);
      v8bf a1 = ldfrag(A_s, wr * 32 + 16 + ln, kb);
      v8bf b0 = ldfrag(B_s, wc * 32 + ln,      kb);
      v8bf b1 = ldfrag(B_s, wc * 32 + 16 + ln, kb);
      acc[0][0] = __builtin_amdgcn_mfma_f32_16x16x32_bf16(a0, b0, acc[0][0], 0, 0, 0);
      acc[0][1] = __builtin_amdgcn_mfma_f32_16x16x32_bf16(a0, b1, acc[0][1], 0, 0, 0);
      acc[1][0] = __builtin_amdgcn_mfma_f32_16x16x32_bf16(a1, b0, acc[1][0], 0, 0, 0);
      acc[1][1] = __builtin_amdgcn_mfma_f32_16x16x32_bf16(a1, b1, acc[1][1], 0, 0, 0);
    }

    uint32_t tb = 0;
    #pragma unroll
    for (int rs = 0; rs < 2; ++rs) {
      float sv[2][4];
      float tmax[4];
      #pragma unroll
      for (int i = 0; i < 4; ++i) tmax[i] = -3e38f;
      #pragma unroll
      for (int cs = 0; cs < 2; ++cs) {
        #pragma unroll
        for (int i = 0; i < 4; ++i) {
          int qr = wr * 32 + rs * 16 + g * 4 + i;
          int p  = j * 128 + wc * 32 + cs * 16 + ln;
          int mk = mask[mbase + ((size_t)qr << 12) + p];
          float s = mk ? acc[rs][cs][i] : -1e9f;
          tb |= (uint32_t)(mk != 0) << (rs * 8 + cs * 4 + i);
          sv[cs][i] = s;
          tmax[i] = fmaxf(tmax[i], s);
        }
      }
      #pragma unroll
      for (int i = 0; i < 4; ++i) {
        #pragma unroll
        for (int xm = 1; xm < 16; xm <<= 1)
          tmax[i] = fmaxf(tmax[i], __shfl_xor(tmax[i], xm, 64));
      }
      #pragma unroll
      for (int i = 0; i < 4; ++i) {
        float mn = fmaxf(m_run[rs][i], tmax[i]);
        float ts = __expf(sv[0][i] - mn) + __expf(sv[1][i] - mn);
        #pragma unroll
        for (int xm = 1; xm < 16; xm <<= 1) ts += __shfl_xor(ts, xm, 64);
        l_run[rs][i] = l_run[rs][i] * __expf(m_run[rs][i] - mn) + ts;
        m_run[rs][i] = mn;
      }
    }
    if (j & 1) wsb[(j >> 1) * 512 + t] = curbits | (tb << 16);
    else       curbits = tb;
  }

  // ---------------- merge m/l across the 4 col-waves ----------------
  __syncthreads();
  if (ln == 0) {
    #pragma unroll
    for (int rs = 0; rs < 2; ++rs)
      #pragma unroll
      for (int i = 0; i < 4; ++i) {
        int row = wr * 32 + rs * 16 + g * 4 + i;
        mW[wc][row] = m_run[rs][i];
        lW[wc][row] = l_run[rs][i];
      }
  }
  __syncthreads();
  if (t < 64) {
    float mf = -3e38f;
    #pragma unroll
    for (int k = 0; k < 4; ++k) mf = fmaxf(mf, mW[k][t]);
    float lf = 0.f;
    #pragma unroll
    for (int k = 0; k < 4; ++k) lf += lW[k][t] * __expf(mW[k][t] - mf);
    mfin[t] = mf;
    lfin[t] = 1.f / lf;
  }
  __syncthreads();

  float mfr[2][4], lir[2][4];
  #pragma unroll
  for (int rs = 0; rs < 2; ++rs)
    #pragma unroll
    for (int i = 0; i < 4; ++i) {
      int row = wr * 32 + rs * 16 + g * 4 + i;
      mfr[rs][i] = mfin[row];
      lir[rs][i] = lfin[row];
    }

  // ---------------- PASS B: recompute, scale, write ----------------
  for (int j = 0; j < 32; ++j) {
    __syncthreads();
    #pragma unroll
    for (int jj = 0; jj < 4; ++jj) {
      int c = t * 4 + jj;
      int row = c >> 4, slot = c & 15;
      u32x4 v = *(const u32x4*)(ctxb + (size_t)(j * 128 + row) * KP + slot * 8);
      *(u32x4*)((char*)B_s + row * 256 + ((slot * 16) ^ ((row & 7) << 4))) = v;
    }
    __syncthreads();

    v4f acc[2][2];
    #pragma unroll
    for (int rs = 0; rs < 2; ++rs)
      #pragma unroll
      for (int cs = 0; cs < 2; ++cs) acc[rs][cs] = (v4f){0.f, 0.f, 0.f, 0.f};
    #pragma unroll
    for (int kk = 0; kk < 4; ++kk) {
      int kb = kk * 64 + g * 16;
      v8bf a0 = ldfrag(A_s, wr * 32 + ln,      kb);
      v8bf a1 = ldfrag(A_s, wr * 32 + 16 + ln, kb);
      v8bf b0 = ldfrag(B_s, wc * 32 + ln,      kb);
      v8bf b1 = ldfrag(B_s, wc * 32 + 16 + ln, kb);
      acc[0][0] = __builtin_amdgcn_mfma_f32_16x16x32_bf16(a0, b0, acc[0][0], 0, 0, 0);
      acc[0][1] = __builtin_amdgcn_mfma_f32_16x16x32_bf16(a0, b1, acc[0][1], 0, 0, 0);
      acc[1][0] = __builtin_amdgcn_mfma_f32_16x16x32_bf16(a1, b0, acc[1][0], 0, 0, 0);
      acc[1][1] = __builtin_amdgcn_mfma_f32_16x16x32_bf16(a1, b1, acc[1][1], 0, 0, 0);
    }

    uint32_t bits = wsb[(j >> 1) * 512 + t] >> ((j & 1) * 16);
    #pragma unroll
    for (int rs = 0; rs < 2; ++rs) {
      #pragma unroll
      for (int cs = 0; cs < 2; ++cs) {
        #pragma unroll
        for (int i = 0; i < 4; ++i) {
          int qr = wr * 32 + rs * 16 + g * 4 + i;
          int p  = j * 128 + wc * 32 + cs * 16 + ln;
          float s = ((bits >> (rs * 8 + cs * 4 + i)) & 1u) ? acc[rs][cs][i] : -1e9f;
          out[mbase + ((size_t)qr << 12) + p] = __expf(s - mfr[rs][i]) * lir[rs][i];
        }
      }
    }
  }
}

// -------------------------------------------------------------------------
extern "C" void kernel_launch(void* const* d_in, const int* in_sizes, int n_in,
                              void* d_out, int out_size, void* d_ws, size_t ws_size,
                              hipStream_t stream) {
  const float* query = (const float*)d_in[0];
  const int*   mask  = (const int*)d_in[1];
  const float* w_q   = (const float*)d_in[2];
  const float* b_q   = (const float*)d_in[3];
  const float* wt    = (const float*)d_in[4];
  float* out = (float*)d_out;

  ushort* ctx = (ushort*)d_ws;                                   // 8.4 MB
  uint32_t* wsbits = (uint32_t*)((char*)d_ws +
      (size_t)BATCH * SEQ * KP * sizeof(ushort));                // +16.8 MB

  ctx_kernel<<<dim3(BATCH * SEQ / 64), dim3(256), 0, stream>>>(query, w_q, b_q, wt, ctx);
  attn_kernel<<<dim3(BATCH * SEQ / 64), dim3(512), 0, stream>>>(ctx, mask, wsbits, out);
}

// Round 2
// 356.365 us; speedup vs baseline: 1.4579x; 1.4579x over previous
//
#include <hip/hip_runtime.h>
#include <hip/hip_bf16.h>
#include <stdint.h>

#define BATCH 8
#define SEQ   4096
#define DM    512
#define HD    120
#define KP    128   // padded k-dim (120 -> 128, zero pad)

typedef __bf16   v8bf  __attribute__((ext_vector_type(8)));
typedef float    v4f   __attribute__((ext_vector_type(4)));
typedef uint32_t u32x4 __attribute__((ext_vector_type(4)));
typedef uint32_t u32x2 __attribute__((ext_vector_type(2)));
typedef float    f32x4 __attribute__((ext_vector_type(4)));

static __device__ __forceinline__ ushort f2bf(float x) {
  uint32_t u = __builtin_bit_cast(uint32_t, x);
  return (ushort)((u + 0x7fffu + ((u >> 16) & 1u)) >> 16);
}

// async global->LDS, 16B per lane. LDS base must be wave-uniform; global addr per-lane.
static __device__ __forceinline__ void gld16(const void* g, void* l) {
  __builtin_amdgcn_global_load_lds(
      (const __attribute__((address_space(1))) uint32_t*)g,
      (__attribute__((address_space(3))) uint32_t*)l, 16, 0, 0);
}

template <int NC>
static __device__ __forceinline__ void stage(const char* gsrc, char* lbase, int w, int lane) {
  #pragma unroll
  for (int i = 0; i < NC; ++i)
    gld16(gsrc + (w * NC + i) * 1024 + lane * 16, lbase + (w * NC + i) * 1024);
}

// -------------------------------------------------------------------------
// Kernel 1: ctx_n = normalize((q @ w_q^T + b_q) * wt) -> bf16 [B*S][128],
// stored PRE-SWIZZLED (byte_in_row = slot*16 ^ ((row&7)<<4)) so attn staging
// is a linear copy. f32 on VALU for precision. 512 blocks x 256 threads.
// -------------------------------------------------------------------------
__global__ __launch_bounds__(256) void ctx_kernel(
    const float* __restrict__ q, const float* __restrict__ wq,
    const float* __restrict__ bq, const float* __restrict__ wt,
    ushort* __restrict__ ctx)
{
  __shared__ __align__(16) float qs[32][68];    // [kk][row], stride 272B (16B mult)
  __shared__ __align__(16) float ws2[32][136];  // [kk][col], stride 544B

  const int t  = threadIdx.x;
  const int tx = t & 31, ty = t >> 5;           // thread: rows ty*8..+7, cols tx*4..+3
  const size_t row0 = (size_t)blockIdx.x * 64;
  const int qr = t >> 2, qk = (t & 3) * 8;      // q-load mapping

  float acc[8][4];
  #pragma unroll
  for (int j = 0; j < 8; ++j)
    #pragma unroll
    for (int i = 0; i < 4; ++i) acc[j][i] = 0.f;

  for (int k0 = 0; k0 < DM; k0 += 32) {
    __syncthreads();
    {  // q chunk 64x32, transposed into qs[kk][row]
      f32x4 v0 = *(const f32x4*)&q[(row0 + qr) * DM + k0 + qk];
      f32x4 v1 = *(const f32x4*)&q[(row0 + qr) * DM + k0 + qk + 4];
      #pragma unroll
      for (int i = 0; i < 4; ++i) qs[qk + i][qr] = v0[i];
      #pragma unroll
      for (int i = 0; i < 4; ++i) qs[qk + 4 + i][qr] = v1[i];
    }
    #pragma unroll
    for (int i = 0; i < 16; ++i) {   // w chunk 32x128 (transposed), zero pad c>=120
      int flat = t + i * 256;
      int kk = flat & 31, c = flat >> 5;
      ws2[kk][c] = (c < HD) ? wq[c * DM + k0 + kk] : 0.f;
    }
    __syncthreads();
    #pragma unroll
    for (int kk = 0; kk < 32; ++kk) {
      f32x4 b  = *(const f32x4*)&ws2[kk][tx * 4];
      f32x4 a0 = *(const f32x4*)&qs[kk][ty * 8];
      f32x4 a1 = *(const f32x4*)&qs[kk][ty * 8 + 4];
      #pragma unroll
      for (int r = 0; r < 4; ++r)
        #pragma unroll
        for (int c = 0; c < 4; ++c) {
          acc[r][c]     = fmaf(a0[r], b[c], acc[r][c]);
          acc[4 + r][c] = fmaf(a1[r], b[c], acc[4 + r][c]);
        }
    }
  }

  float wtv[4], bqv[4];
  #pragma unroll
  for (int i = 0; i < 4; ++i) {
    int c = tx * 4 + i;
    wtv[i] = (c < HD) ? wt[c] : 0.f;
    bqv[i] = (c < HD) ? bq[c] : 0.f;
  }
  #pragma unroll
  for (int j = 0; j < 8; ++j) {
    int r = ty * 8 + j;
    float v[4]; float ss = 0.f;
    #pragma unroll
    for (int i = 0; i < 4; ++i) {
      v[i] = (acc[j][i] + bqv[i]) * wtv[i];
      ss = fmaf(v[i], v[i], ss);
    }
    #pragma unroll
    for (int xm = 1; xm < 32; xm <<= 1) ss += __shfl_xor(ss, xm, 64);
    float rinv = 1.f / fmaxf(sqrtf(ss), 1e-12f);
    uint32_t p0 = (uint32_t)f2bf(v[0] * rinv) | ((uint32_t)f2bf(v[1] * rinv) << 16);
    uint32_t p1 = (uint32_t)f2bf(v[2] * rinv) | ((uint32_t)f2bf(v[3] * rinv) << 16);
    u32x2 o = {p0, p1};
    char* dst = (char*)ctx + (row0 + r) * 256 +
                (((tx >> 1) * 16) ^ ((r & 7) << 4)) + (tx & 1) * 8;
    *(u32x2*)dst = o;
  }
}

// -------------------------------------------------------------------------
// Kernel 2: scores + mask + softmax with FIXED max = 1.0 (scores are dots of
// unit vectors, |s| <= ~1.01). Pass A: per-thread sum of exp(s-1) + mask-bit
// packing. Pass B: recompute scores, scale, write. Double-buffered B tile via
// global_load_lds; mask prefetched one iter ahead. 512 blocks x 512 threads.
// -------------------------------------------------------------------------
static __device__ __forceinline__ v8bf ldfrag(const char* base, int row, int kb) {
  int byte = row * 256 + (kb ^ ((row & 7) << 4));
  return __builtin_bit_cast(v8bf, *(const u32x4*)(base + byte));
}

#define DO_MFMA(BUF, ACC)                                                        \
  _Pragma("unroll")                                                              \
  for (int kk = 0; kk < 4; ++kk) {                                               \
    int kb = kk * 64 + g * 16;                                                   \
    v8bf a0 = ldfrag(A_s, wr * 32 + ln, kb);                                     \
    v8bf a1 = ldfrag(A_s, wr * 32 + 16 + ln, kb);                                \
    v8bf b0 = ldfrag(BUF, wc * 32 + ln, kb);                                     \
    v8bf b1 = ldfrag(BUF, wc * 32 + 16 + ln, kb);                                \
    ACC[0][0] = __builtin_amdgcn_mfma_f32_16x16x32_bf16(a0, b0, ACC[0][0], 0, 0, 0); \
    ACC[0][1] = __builtin_amdgcn_mfma_f32_16x16x32_bf16(a0, b1, ACC[0][1], 0, 0, 0); \
    ACC[1][0] = __builtin_amdgcn_mfma_f32_16x16x32_bf16(a1, b0, ACC[1][0], 0, 0, 0); \
    ACC[1][1] = __builtin_amdgcn_mfma_f32_16x16x32_bf16(a1, b1, ACC[1][1], 0, 0, 0); \
  }

#define LOADM(dst, jj)                                                           \
  do {                                                                           \
    int joff = (jj) * 128;                                                       \
    _Pragma("unroll") for (int rs = 0; rs < 2; ++rs)                             \
    _Pragma("unroll") for (int i2 = 0; i2 < 4; ++i2)                             \
    _Pragma("unroll") for (int cs = 0; cs < 2; ++cs)                             \
      dst[rs * 8 + cs * 4 + i2] = mrow[rs][i2][joff + cs * 16];                  \
  } while (0)

__global__ __launch_bounds__(512) void attn_kernel(
    const ushort* __restrict__ ctx, const int* __restrict__ mask,
    uint32_t* __restrict__ wsbits, float* __restrict__ out)
{
  __shared__ __align__(16) char lds[81920];
  char* A_s = lds;            // 16 KB, valid for both passes
  char* B0  = lds + 16384;    // 32 KB
  char* B1  = lds + 49152;    // 32 KB
  float* lW   = (float*)B1;          // merge scratch aliases B1 (safe: see barriers)
  float* lfin = (float*)(B1 + 1024);

  const int t    = threadIdx.x;
  const int b    = blockIdx.x & 7;          // batch -> XCD-local ctx in L2
  const int tile = blockIdx.x >> 3;
  const int r0   = tile * 64;
  const int w    = t >> 6, lane = t & 63;
  const int wr   = w >> 2, wc = w & 3;      // wave tile 32x32
  const int g    = lane >> 4, ln = lane & 15;
  const char* ctxb = (const char*)ctx + (size_t)b * SEQ * 256;
  uint32_t* wsb = wsbits + (size_t)blockIdx.x * (512 * 16);
  const size_t mbase = ((size_t)b << 24) + ((size_t)r0 << 12);

  const int* mrow[2][4];
  #pragma unroll
  for (int rs = 0; rs < 2; ++rs)
    #pragma unroll
    for (int i = 0; i < 4; ++i) {
      int qrr = wr * 32 + rs * 16 + g * 4 + i;
      mrow[rs][i] = mask + mbase + ((size_t)qrr << 12) + wc * 32 + ln;
    }

  // ---------------- prologue ----------------
  stage<2>(ctxb + (size_t)r0 * 256, A_s, w, lane);
  stage<4>(ctxb, B0, w, lane);
  int mcur[16];
  LOADM(mcur, 0);
  __syncthreads();

  float lpart[2][4];
  #pragma unroll
  for (int rs = 0; rs < 2; ++rs)
    #pragma unroll
    for (int i = 0; i < 4; ++i) lpart[rs][i] = 0.f;
  uint32_t curbits = 0;

  // ---------------- PASS A ----------------
  for (int j = 0; j < 32; ++j) {
    char* cur = (j & 1) ? B1 : B0;
    char* nxt = (j & 1) ? B0 : B1;
    if (j < 31) stage<4>(ctxb + (size_t)((j + 1) * 128) * 256, nxt, w, lane);
    int mnext[16];
    if (j < 31) LOADM(mnext, j + 1);

    v4f acc[2][2];
    #pragma unroll
    for (int rs = 0; rs < 2; ++rs)
      #pragma unroll
      for (int cs = 0; cs < 2; ++cs) acc[rs][cs] = (v4f){0.f, 0.f, 0.f, 0.f};
    DO_MFMA(cur, acc);

    uint32_t tb = 0;
    #pragma unroll
    for (int rs = 0; rs < 2; ++rs)
      #pragma unroll
      for (int cs = 0; cs < 2; ++cs)
        #pragma unroll
        for (int i = 0; i < 4; ++i) {
          int mk = mcur[rs * 8 + cs * 4 + i];
          float e = mk ? __expf(acc[rs][cs][i] - 1.0f) : 0.0f;
          lpart[rs][i] += e;
          tb |= (uint32_t)(mk != 0) << (rs * 8 + cs * 4 + i);
        }
    if (j & 1) wsb[(j >> 1) * 512 + t] = curbits | (tb << 16);
    else       curbits = tb;
    if (j < 31) {
      #pragma unroll
      for (int x = 0; x < 16; ++x) mcur[x] = mnext[x];
    }
    __syncthreads();
  }

  // ---------------- merge l across 16 lanes + 4 col-waves ----------------
  #pragma unroll
  for (int rs = 0; rs < 2; ++rs)
    #pragma unroll
    for (int i = 0; i < 4; ++i) {
      float s = lpart[rs][i];
      #pragma unroll
      for (int xm = 1; xm < 16; xm <<= 1) s += __shfl_xor(s, xm, 64);
      lpart[rs][i] = s;
    }
  if (ln == 0) {
    #pragma unroll
    for (int rs = 0; rs < 2; ++rs)
      #pragma unroll
      for (int i = 0; i < 4; ++i)
        lW[wc * 64 + wr * 32 + rs * 16 + g * 4 + i] = lpart[rs][i];
  }
  __syncthreads();
  if (t < 64) {
    float lf = lW[t] + lW[64 + t] + lW[128 + t] + lW[192 + t];
    lfin[t] = (lf > 0.f) ? (1.f / lf) : 0.f;
  }
  __syncthreads();
  float lir[2][4];
  #pragma unroll
  for (int rs = 0; rs < 2; ++rs)
    #pragma unroll
    for (int i = 0; i < 4; ++i)
      lir[rs][i] = lfin[wr * 32 + rs * 16 + g * 4 + i];

  // ---------------- PASS B ----------------
  stage<4>(ctxb, B0, w, lane);
  uint32_t bcur = wsb[t];
  uint32_t bnext = 0;
  __syncthreads();   // lir reads completed before this barrier; B1 overwritten after

  for (int j = 0; j < 32; ++j) {
    char* cur = (j & 1) ? B1 : B0;
    char* nxt = (j & 1) ? B0 : B1;
    if (j < 31) stage<4>(ctxb + (size_t)((j + 1) * 128) * 256, nxt, w, lane);
    if (!(j & 1) && j < 30) bnext = wsb[((j >> 1) + 1) * 512 + t];

    v4f acc[2][2];
    #pragma unroll
    for (int rs = 0; rs < 2; ++rs)
      #pragma unroll
      for (int cs = 0; cs < 2; ++cs) acc[rs][cs] = (v4f){0.f, 0.f, 0.f, 0.f};
    DO_MFMA(cur, acc);

    uint32_t bits = bcur >> ((j & 1) * 16);
    #pragma unroll
    for (int rs = 0; rs < 2; ++rs)
      #pragma unroll
      for (int cs = 0; cs < 2; ++cs)
        #pragma unroll
        for (int i = 0; i < 4; ++i) {
          int qrr = wr * 32 + rs * 16 + g * 4 + i;
          size_t off = mbase + ((size_t)qrr << 12) + j * 128 + wc * 32 + cs * 16 + ln;
          float val = ((bits >> (rs * 8 + cs * 4 + i)) & 1u)
                        ? __expf(acc[rs][cs][i] - 1.0f) * lir[rs][i] : 0.0f;
          __builtin_nontemporal_store(val, out + off);
        }
    if (j & 1) bcur = bnext;
    __syncthreads();
  }
}

// -------------------------------------------------------------------------
extern "C" void kernel_launch(void* const* d_in, const int* in_sizes, int n_in,
                              void* d_out, int out_size, void* d_ws, size_t ws_size,
                              hipStream_t stream) {
  const float* query = (const float*)d_in[0];
  const int*   mask  = (const int*)d_in[1];
  const float* w_q   = (const float*)d_in[2];
  const float* b_q   = (const float*)d_in[3];
  const float* wt    = (const float*)d_in[4];
  float* out = (float*)d_out;

  ushort* ctx = (ushort*)d_ws;                                   // 8.4 MB
  uint32_t* wsbits = (uint32_t*)((char*)d_ws +
      (size_t)BATCH * SEQ * KP * sizeof(ushort));                // +16.8 MB

  ctx_kernel<<<dim3(BATCH * SEQ / 64), dim3(256), 0, stream>>>(query, w_q, b_q, wt, ctx);
  attn_kernel<<<dim3(BATCH * SEQ / 64), dim3(512), 0, stream>>>(ctx, mask, wsbits, out);
}